// Round 2
// baseline (436.399 us; speedup 1.0000x reference)
//
#include <hip/hip_runtime.h>

// GCN layer: out = segment_sum(L_vals[:,None] * X[L_cols], L_rows) @ W^T + b
//
// Round-2 strategy (atomic-RMW was the bottleneck: 102.4M device-scope fp32
// atomics = 400MB memory-side writes, 349us):
//   Linear commutes with aggregation:
//     out = segsum(val * (X@W^T)[col], row) + b
//   1) Y = X @ W^T                  (wave/row, shfl + LDS-staged W)
//   2) CSR-ize edges per launch     (histogram -> 3-kernel scan -> scatter)
//   3) out[r] = b + sum val*Y[col]  (pure gather, wave/row, no atomics)
// fp32 atomics: 102.4M -> 0. int atomics: 3.2M.
// Fallback to round-1 atomic path if ws_size too small.

constexpr int D  = 64;
constexpr int NN = 100000;   // nodes
constexpr int NE = 1600000;  // edges
constexpr int SCAN_N   = NN + 1;                       // off[] elements scanned
constexpr int NTILES   = (SCAN_N + 1023) / 1024;       // 98
// ws layout (bytes, all 256-aligned)
constexpr size_t WS_Y     = 0;                          // 25,600,000 B
constexpr size_t WS_OFF   = 25600000;                   // 100352 ints
constexpr size_t WS_TSUM  = WS_OFF  + 4 * 100352;       // 128 ints
constexpr size_t WS_COLS  = WS_TSUM + 512;              // NE ints
constexpr size_t WS_VALS  = WS_COLS + 4ull * NE;        // NE floats
constexpr size_t WS_NEED  = WS_VALS + 4ull * NE;        // 38,801,920 B

// ---------- 1) Y = X @ W^T : one wave per row ----------
__global__ __launch_bounds__(256) void gcn_ybuild(
    const float* __restrict__ X, const float* __restrict__ W,
    float* __restrict__ Y)
{
    __shared__ float Wl[D][D + 1];        // +1 pad: 2-way wave64 conflict = free
    const int tid = threadIdx.x;
    for (int i = tid; i < D * D; i += 256)
        Wl[i >> 6][i & 63] = W[i];
    __syncthreads();

    const int wave = tid >> 6, lane = tid & 63;
    const int n = blockIdx.x * 4 + wave;  // NN % 4 == 0
    const float x = X[n * D + lane];
    float acc = 0.f;
#pragma unroll
    for (int f = 0; f < D; ++f)
        acc += __shfl(x, f) * Wl[lane][f];
    Y[n * D + lane] = acc;
}

// ---------- 2a) histogram: off[r+1] += 1 ----------
__global__ __launch_bounds__(256) void gcn_hist(
    const int* __restrict__ rows, int* __restrict__ off)
{
    const int e = blockIdx.x * 256 + threadIdx.x;   // NE % 256 == 0
    atomicAdd(&off[rows[e] + 1], 1);
}

// ---------- 2b) scan pass 1: per-1024 tile inclusive scan ----------
__global__ __launch_bounds__(1024) void gcn_scan1(
    int* __restrict__ off, int* __restrict__ tsum)
{
    const int tile = blockIdx.x;
    const int i = tile * 1024 + threadIdx.x;
    const int lane = threadIdx.x & 63, wid = threadIdx.x >> 6;
    int acc = (i < SCAN_N) ? off[i] : 0;
#pragma unroll
    for (int s = 1; s < 64; s <<= 1) {
        int t = __shfl_up(acc, s);
        if (lane >= s) acc += t;
    }
    __shared__ int wsum[16];
    if (lane == 63) wsum[wid] = acc;
    __syncthreads();
    if (wid == 0) {
        int wv = (lane < 16) ? wsum[lane] : 0;
#pragma unroll
        for (int s = 1; s < 16; s <<= 1) {
            int t = __shfl_up(wv, s);
            if (lane >= s) wv += t;
        }
        if (lane < 16) wsum[lane] = wv;
    }
    __syncthreads();
    if (wid > 0) acc += wsum[wid - 1];
    if (i < SCAN_N) off[i] = acc;
    if (threadIdx.x == 1023) tsum[tile] = acc;   // tile total
}

// ---------- 2c) scan pass 2: inclusive scan of tile sums (1 block) ----------
__global__ __launch_bounds__(128) void gcn_scan2(int* __restrict__ tsum)
{
    const int tid = threadIdx.x, lane = tid & 63, wid = tid >> 6;
    int acc = (tid < NTILES) ? tsum[tid] : 0;
#pragma unroll
    for (int s = 1; s < 64; s <<= 1) {
        int t = __shfl_up(acc, s);
        if (lane >= s) acc += t;
    }
    __shared__ int w0;
    if (wid == 0 && lane == 63) w0 = acc;
    __syncthreads();
    if (wid == 1) acc += w0;
    if (tid < NTILES) tsum[tid] = acc;
}

// ---------- 2d) scan pass 3: add tile prefixes (tiles 1..NTILES-1) ----------
__global__ __launch_bounds__(1024) void gcn_scan3(
    int* __restrict__ off, const int* __restrict__ tsum)
{
    const int tile = blockIdx.x + 1;
    const int i = tile * 1024 + threadIdx.x;
    if (i < SCAN_N) off[i] += tsum[tile - 1];
}

// ---------- 2e) stable-ish scatter into CSR order ----------
// off[r] (= row start) is bumped to row end as a side effect.
__global__ __launch_bounds__(256) void gcn_csr_scatter(
    const int* __restrict__ rows, const int* __restrict__ cols,
    const float* __restrict__ vals, int* __restrict__ off,
    int* __restrict__ cols_s, float* __restrict__ vals_s)
{
    const int e = blockIdx.x * 256 + threadIdx.x;   // NE % 256 == 0
    const int r = rows[e];
    const int pos = atomicAdd(&off[r], 1);
    cols_s[pos] = cols[e];
    vals_s[pos] = vals[e];
}

// ---------- 3) gather-aggregate: out[r] = b + sum val * Y[col] ----------
// Post-scatter: off[r] = end of row r; start = off[r-1] (0 for r==0).
__global__ __launch_bounds__(256) void gcn_aggregate(
    const int* __restrict__ off, const int* __restrict__ cols_s,
    const float* __restrict__ vals_s, const float* __restrict__ Y,
    const float* __restrict__ bias, float* __restrict__ out)
{
    const int wave = threadIdx.x >> 6, lane = threadIdx.x & 63;
    const int r = blockIdx.x * 4 + wave;            // NN % 4 == 0
    const int start = (r == 0) ? 0 : off[r - 1];
    const int end   = off[r];
    float acc = bias[lane];
    for (int j = start; j < end; ++j) {
        const int   c = cols_s[j];
        const float v = vals_s[j];
        acc = fmaf(v, Y[c * D + lane], acc);
    }
    out[r * D + lane] = acc;
}

// ---------- fallback (round-1 proven path) ----------
__global__ __launch_bounds__(256) void gcn_scatter_kernel(
    const int* __restrict__ rows, const int* __restrict__ cols,
    const float* __restrict__ vals, const float* __restrict__ X,
    float* __restrict__ agg)
{
    const int e    = blockIdx.x * 4 + (threadIdx.x >> 6);
    const int lane = threadIdx.x & 63;
    atomicAdd(&agg[rows[e] * D + lane], vals[e] * X[cols[e] * D + lane]);
}

__global__ __launch_bounds__(256) void gcn_transform_kernel(
    const float* __restrict__ W, const float* __restrict__ bias,
    float* __restrict__ out)
{
    __shared__ float Wl[D][D + 1];
    __shared__ float rowbuf[4][D];
    const int tid = threadIdx.x;
    for (int i = tid; i < D * D; i += 256)
        Wl[i >> 6][i & 63] = W[i];
    const int wave = tid >> 6, lane = tid & 63;
    const int n = blockIdx.x * 4 + wave;
    rowbuf[wave][lane] = out[n * D + lane];
    __syncthreads();
    float acc = bias[lane];
#pragma unroll
    for (int f = 0; f < D; ++f)
        acc += rowbuf[wave][f] * Wl[lane][f];
    out[n * D + lane] = acc;
}

extern "C" void kernel_launch(void* const* d_in, const int* in_sizes, int n_in,
                              void* d_out, int out_size, void* d_ws, size_t ws_size,
                              hipStream_t stream) {
    const int*   L_rows = (const int*)d_in[0];
    const int*   L_cols = (const int*)d_in[1];
    const float* L_vals = (const float*)d_in[2];
    const float* X      = (const float*)d_in[3];
    const float* W      = (const float*)d_in[4];
    const float* b      = (const float*)d_in[5];
    float* out = (float*)d_out;

    if (ws_size >= WS_NEED) {
        char* w = (char*)d_ws;
        float* Y      = (float*)(w + WS_Y);
        int*   off    = (int*)  (w + WS_OFF);
        int*   tsum   = (int*)  (w + WS_TSUM);
        int*   cols_s = (int*)  (w + WS_COLS);
        float* vals_s = (float*)(w + WS_VALS);

        // zero off + tsum (adjacent)
        hipMemsetAsync(off, 0, 4 * 100352 + 512, stream);

        gcn_ybuild<<<NN / 4, 256, 0, stream>>>(X, W, Y);
        gcn_hist<<<NE / 256, 256, 0, stream>>>(L_rows, off);
        gcn_scan1<<<NTILES, 1024, 0, stream>>>(off, tsum);
        gcn_scan2<<<1, 128, 0, stream>>>(tsum);
        gcn_scan3<<<NTILES - 1, 1024, 0, stream>>>(off, tsum);
        gcn_csr_scatter<<<NE / 256, 256, 0, stream>>>(L_rows, L_cols, L_vals,
                                                      off, cols_s, vals_s);
        gcn_aggregate<<<NN / 4, 256, 0, stream>>>(off, cols_s, vals_s, Y, b, out);
    } else {
        // fallback: atomic scatter + in-place transform
        hipMemsetAsync(out, 0, (size_t)out_size * sizeof(float), stream);
        gcn_scatter_kernel<<<NE / 4, 256, 0, stream>>>(L_rows, L_cols, L_vals, X, out);
        gcn_transform_kernel<<<NN / 4, 256, 0, stream>>>(W, b, out);
    }
}

// Round 3
// 433.695 us; speedup vs baseline: 1.0062x; 1.0062x over previous
//
#include <hip/hip_runtime.h>

// GCN layer: out = segment_sum(L_vals[:,None] * X[L_cols], L_rows) @ W^T + b
//
// Round-3: same CSR pipeline as round-2, de-dumbed:
//   - aggregate: unroll-by-8 edge loop (8 concurrent Y-gathers per wave; was
//     MLP=1, VGPR=8, latency-bound at 146us)
//   - csr_scatter: single packed int2 (col,val) store per edge (was 2 random
//     4B stores to separate arrays -> 2x write-allocate amplification)
//   - ybuild: W in 64 VGPRs/lane + wave-uniform float4 LDS broadcast of x
//     (was 128 LDS ops/wave via shfl+W-reads)
// Fallback to round-1 atomic path if ws_size too small.

constexpr int D  = 64;
constexpr int NN = 100000;   // nodes
constexpr int NE = 1600000;  // edges
constexpr int SCAN_N = NN + 1;
constexpr int NTILES = (SCAN_N + 1023) / 1024;       // 98
// ws layout (bytes)
constexpr size_t WS_Y    = 0;                         // NN*D floats = 25.6 MB
constexpr size_t WS_OFF  = 25600000;                  // 100352 ints
constexpr size_t WS_TSUM = WS_OFF + 4 * 100352;       // 128 ints
constexpr size_t WS_EDG  = WS_TSUM + 512;             // NE int2 = 12.8 MB
constexpr size_t WS_NEED = WS_EDG + 8ull * NE;        // ~38.8 MB

// ---------- 1) Y = X @ W^T : one wave per row, W in VGPRs ----------
__global__ __launch_bounds__(256) void gcn_ybuild(
    const float* __restrict__ X, const float* __restrict__ W,
    float* __restrict__ Y)
{
    __shared__ float xs[4][D];
    const int tid = threadIdx.x, wave = tid >> 6, lane = tid & 63;

    // lane o holds W[o][0..63] in registers (static indexing -> VGPRs)
    float Wr[D];
#pragma unroll
    for (int k = 0; k < D / 4; ++k) {
        const float4 w4 = *(const float4*)&W[lane * D + 4 * k];
        Wr[4 * k + 0] = w4.x; Wr[4 * k + 1] = w4.y;
        Wr[4 * k + 2] = w4.z; Wr[4 * k + 3] = w4.w;
    }

    const int n = blockIdx.x * 4 + wave;  // NN % 4 == 0
    xs[wave][lane] = X[n * D + lane];
    __syncthreads();

    float acc = 0.f;
#pragma unroll
    for (int k = 0; k < D / 4; ++k) {
        const float4 x4 = *(const float4*)&xs[wave][4 * k];  // wave-uniform: broadcast
        acc = fmaf(x4.x, Wr[4 * k + 0], acc);
        acc = fmaf(x4.y, Wr[4 * k + 1], acc);
        acc = fmaf(x4.z, Wr[4 * k + 2], acc);
        acc = fmaf(x4.w, Wr[4 * k + 3], acc);
    }
    Y[n * D + lane] = acc;
}

// ---------- 2a) histogram ----------
__global__ __launch_bounds__(256) void gcn_hist(
    const int* __restrict__ rows, int* __restrict__ off)
{
    const int e = blockIdx.x * 256 + threadIdx.x;   // NE % 256 == 0
    atomicAdd(&off[rows[e] + 1], 1);
}

// ---------- 2b) scan pass 1: per-1024 tile inclusive scan ----------
__global__ __launch_bounds__(1024) void gcn_scan1(
    int* __restrict__ off, int* __restrict__ tsum)
{
    const int tile = blockIdx.x;
    const int i = tile * 1024 + threadIdx.x;
    const int lane = threadIdx.x & 63, wid = threadIdx.x >> 6;
    int acc = (i < SCAN_N) ? off[i] : 0;
#pragma unroll
    for (int s = 1; s < 64; s <<= 1) {
        int t = __shfl_up(acc, s);
        if (lane >= s) acc += t;
    }
    __shared__ int wsum[16];
    if (lane == 63) wsum[wid] = acc;
    __syncthreads();
    if (wid == 0) {
        int wv = (lane < 16) ? wsum[lane] : 0;
#pragma unroll
        for (int s = 1; s < 16; s <<= 1) {
            int t = __shfl_up(wv, s);
            if (lane >= s) wv += t;
        }
        if (lane < 16) wsum[lane] = wv;
    }
    __syncthreads();
    if (wid > 0) acc += wsum[wid - 1];
    if (i < SCAN_N) off[i] = acc;
    if (threadIdx.x == 1023) tsum[tile] = acc;
}

// ---------- 2c) scan pass 2: scan of tile sums ----------
__global__ __launch_bounds__(128) void gcn_scan2(int* __restrict__ tsum)
{
    const int tid = threadIdx.x, lane = tid & 63, wid = tid >> 6;
    int acc = (tid < NTILES) ? tsum[tid] : 0;
#pragma unroll
    for (int s = 1; s < 64; s <<= 1) {
        int t = __shfl_up(acc, s);
        if (lane >= s) acc += t;
    }
    __shared__ int w0;
    if (wid == 0 && lane == 63) w0 = acc;
    __syncthreads();
    if (wid == 1) acc += w0;
    if (tid < NTILES) tsum[tid] = acc;
}

// ---------- 2d) scan pass 3: add tile prefixes ----------
__global__ __launch_bounds__(1024) void gcn_scan3(
    int* __restrict__ off, const int* __restrict__ tsum)
{
    const int tile = blockIdx.x + 1;
    const int i = tile * 1024 + threadIdx.x;
    if (i < SCAN_N) off[i] += tsum[tile - 1];
}

// ---------- 2e) scatter into CSR order, packed (col,val) ----------
__global__ __launch_bounds__(256) void gcn_csr_scatter(
    const int* __restrict__ rows, const int* __restrict__ cols,
    const float* __restrict__ vals, int* __restrict__ off,
    int2* __restrict__ edges)
{
    const int e = blockIdx.x * 256 + threadIdx.x;   // NE % 256 == 0
    const int r = rows[e];
    const int pos = atomicAdd(&off[r], 1);
    edges[pos] = make_int2(cols[e], __float_as_int(vals[e]));
}

// ---------- 3) gather-aggregate, unroll-by-8 ----------
__global__ __launch_bounds__(256) void gcn_aggregate(
    const int* __restrict__ off, const int2* __restrict__ edges,
    const float* __restrict__ Y, const float* __restrict__ bias,
    float* __restrict__ out)
{
    const int wave = threadIdx.x >> 6, lane = threadIdx.x & 63;
    const int r = blockIdx.x * 4 + wave;            // NN % 4 == 0
    const int start = (r == 0) ? 0 : off[r - 1];
    const int end   = off[r];
    float acc = bias[lane];
    int j = start;
    for (; j + 8 <= end; j += 8) {
        const int2 e0 = edges[j + 0], e1 = edges[j + 1];
        const int2 e2 = edges[j + 2], e3 = edges[j + 3];
        const int2 e4 = edges[j + 4], e5 = edges[j + 5];
        const int2 e6 = edges[j + 6], e7 = edges[j + 7];
        const float y0 = Y[e0.x * D + lane], y1 = Y[e1.x * D + lane];
        const float y2 = Y[e2.x * D + lane], y3 = Y[e3.x * D + lane];
        const float y4 = Y[e4.x * D + lane], y5 = Y[e5.x * D + lane];
        const float y6 = Y[e6.x * D + lane], y7 = Y[e7.x * D + lane];
        acc = fmaf(__int_as_float(e0.y), y0, acc);
        acc = fmaf(__int_as_float(e1.y), y1, acc);
        acc = fmaf(__int_as_float(e2.y), y2, acc);
        acc = fmaf(__int_as_float(e3.y), y3, acc);
        acc = fmaf(__int_as_float(e4.y), y4, acc);
        acc = fmaf(__int_as_float(e5.y), y5, acc);
        acc = fmaf(__int_as_float(e6.y), y6, acc);
        acc = fmaf(__int_as_float(e7.y), y7, acc);
    }
    for (; j < end; ++j) {
        const int2 e = edges[j];
        acc = fmaf(__int_as_float(e.y), Y[e.x * D + lane], acc);
    }
    out[r * D + lane] = acc;
}

// ---------- fallback (round-1 proven path) ----------
__global__ __launch_bounds__(256) void gcn_scatter_kernel(
    const int* __restrict__ rows, const int* __restrict__ cols,
    const float* __restrict__ vals, const float* __restrict__ X,
    float* __restrict__ agg)
{
    const int e    = blockIdx.x * 4 + (threadIdx.x >> 6);
    const int lane = threadIdx.x & 63;
    atomicAdd(&agg[rows[e] * D + lane], vals[e] * X[cols[e] * D + lane]);
}

__global__ __launch_bounds__(256) void gcn_transform_kernel(
    const float* __restrict__ W, const float* __restrict__ bias,
    float* __restrict__ out)
{
    __shared__ float Wl[D][D + 1];
    __shared__ float rowbuf[4][D];
    const int tid = threadIdx.x;
    for (int i = tid; i < D * D; i += 256)
        Wl[i >> 6][i & 63] = W[i];
    const int wave = tid >> 6, lane = tid & 63;
    const int n = blockIdx.x * 4 + wave;
    rowbuf[wave][lane] = out[n * D + lane];
    __syncthreads();
    float acc = bias[lane];
#pragma unroll
    for (int f = 0; f < D; ++f)
        acc += rowbuf[wave][f] * Wl[lane][f];
    out[n * D + lane] = acc;
}

extern "C" void kernel_launch(void* const* d_in, const int* in_sizes, int n_in,
                              void* d_out, int out_size, void* d_ws, size_t ws_size,
                              hipStream_t stream) {
    const int*   L_rows = (const int*)d_in[0];
    const int*   L_cols = (const int*)d_in[1];
    const float* L_vals = (const float*)d_in[2];
    const float* X      = (const float*)d_in[3];
    const float* W      = (const float*)d_in[4];
    const float* b      = (const float*)d_in[5];
    float* out = (float*)d_out;

    if (ws_size >= WS_NEED) {
        char* w = (char*)d_ws;
        float* Y     = (float*)(w + WS_Y);
        int*   off   = (int*)  (w + WS_OFF);
        int*   tsum  = (int*)  (w + WS_TSUM);
        int2*  edges = (int2*) (w + WS_EDG);

        hipMemsetAsync(off, 0, 4 * 100352 + 512, stream);

        gcn_ybuild<<<NN / 4, 256, 0, stream>>>(X, W, Y);
        gcn_hist<<<NE / 256, 256, 0, stream>>>(L_rows, off);
        gcn_scan1<<<NTILES, 1024, 0, stream>>>(off, tsum);
        gcn_scan2<<<1, 128, 0, stream>>>(tsum);
        gcn_scan3<<<NTILES - 1, 1024, 0, stream>>>(off, tsum);
        gcn_csr_scatter<<<NE / 256, 256, 0, stream>>>(L_rows, L_cols, L_vals,
                                                      off, edges);
        gcn_aggregate<<<NN / 4, 256, 0, stream>>>(off, edges, Y, b, out);
    } else {
        hipMemsetAsync(out, 0, (size_t)out_size * sizeof(float), stream);
        gcn_scatter_kernel<<<NE / 4, 256, 0, stream>>>(L_rows, L_cols, L_vals, X, out);
        gcn_transform_kernel<<<NN / 4, 256, 0, stream>>>(W, b, out);
    }
}

// Round 4
// 315.151 us; speedup vs baseline: 1.3847x; 1.3762x over previous
//
#include <hip/hip_runtime.h>

// GCN layer: out = segment_sum(L_vals[:,None] * X[L_cols], L_rows) @ W^T + b
//
// Round-4: fix ybuild scratch spill (round-3: float Wr[64] -> local memory,
// VGPR=36, 3.3GB scratch traffic, 179us). W now lives in 16 NAMED float4
// locals (SSA, cannot spill to scratch); X staged in LDS, read wave-uniform
// float4 (broadcast). 4 rows/wave, 16 rows/block.
// Rest of pipeline (CSR build + unroll-8 gather aggregate) unchanged.

constexpr int D  = 64;
constexpr int NN = 100000;   // nodes
constexpr int NE = 1600000;  // edges
constexpr int SCAN_N = NN + 1;
constexpr int NTILES = (SCAN_N + 1023) / 1024;       // 98
// ws layout (bytes)
constexpr size_t WS_Y    = 0;                         // NN*D floats = 25.6 MB
constexpr size_t WS_OFF  = 25600000;                  // 100352 ints
constexpr size_t WS_TSUM = WS_OFF + 4 * 100352;       // 128 ints
constexpr size_t WS_EDG  = WS_TSUM + 512;             // NE int2 = 12.8 MB
constexpr size_t WS_NEED = WS_EDG + 8ull * NE;        // ~38.8 MB

// ---------- 1) Y = X @ W^T ----------
// lane = output channel o; W[o][:] in 16 named float4 (64 VGPR, no arrays).
// 4 rows per wave, 16 rows per block (NN/16 = 6250 blocks exactly).
__global__ __launch_bounds__(256) void gcn_ybuild(
    const float* __restrict__ X, const float* __restrict__ W,
    float* __restrict__ Y)
{
    __shared__ float xs[16][D];
    const int tid = threadIdx.x, wave = tid >> 6, lane = tid & 63;
    const int base = blockIdx.x * 16;

    // stage 16 X rows (4 KB), fully coalesced float4
    ((float4*)xs)[tid] = ((const float4*)(X + base * D))[tid];

    // W row for this lane: 16 named float4 = 64 VGPRs
    const float4* W4 = (const float4*)W + lane * 16;
    const float4 w0 = W4[0],  w1 = W4[1],  w2 = W4[2],  w3 = W4[3];
    const float4 w4 = W4[4],  w5 = W4[5],  w6 = W4[6],  w7 = W4[7];
    const float4 w8 = W4[8],  w9 = W4[9],  w10 = W4[10], w11 = W4[11];
    const float4 w12 = W4[12], w13 = W4[13], w14 = W4[14], w15 = W4[15];

    __syncthreads();

    const int r = wave * 4;                 // this wave's first row in block
    float a0 = 0.f, a1 = 0.f, a2 = 0.f, a3 = 0.f;

#define YB_STEP(k, wk)                                               \
    {                                                                \
        const float4 x0 = *(const float4*)&xs[r + 0][4 * (k)];       \
        const float4 x1 = *(const float4*)&xs[r + 1][4 * (k)];       \
        const float4 x2 = *(const float4*)&xs[r + 2][4 * (k)];       \
        const float4 x3 = *(const float4*)&xs[r + 3][4 * (k)];       \
        a0 = fmaf(x0.x, wk.x, a0); a0 = fmaf(x0.y, wk.y, a0);        \
        a0 = fmaf(x0.z, wk.z, a0); a0 = fmaf(x0.w, wk.w, a0);        \
        a1 = fmaf(x1.x, wk.x, a1); a1 = fmaf(x1.y, wk.y, a1);        \
        a1 = fmaf(x1.z, wk.z, a1); a1 = fmaf(x1.w, wk.w, a1);        \
        a2 = fmaf(x2.x, wk.x, a2); a2 = fmaf(x2.y, wk.y, a2);        \
        a2 = fmaf(x2.z, wk.z, a2); a2 = fmaf(x2.w, wk.w, a2);        \
        a3 = fmaf(x3.x, wk.x, a3); a3 = fmaf(x3.y, wk.y, a3);        \
        a3 = fmaf(x3.z, wk.z, a3); a3 = fmaf(x3.w, wk.w, a3);        \
    }
    YB_STEP(0, w0)   YB_STEP(1, w1)   YB_STEP(2, w2)   YB_STEP(3, w3)
    YB_STEP(4, w4)   YB_STEP(5, w5)   YB_STEP(6, w6)   YB_STEP(7, w7)
    YB_STEP(8, w8)   YB_STEP(9, w9)   YB_STEP(10, w10) YB_STEP(11, w11)
    YB_STEP(12, w12) YB_STEP(13, w13) YB_STEP(14, w14) YB_STEP(15, w15)
#undef YB_STEP

    float* yb = Y + (size_t)(base + r) * D + lane;
    yb[0 * D] = a0; yb[1 * D] = a1; yb[2 * D] = a2; yb[3 * D] = a3;
}

// ---------- 2a) histogram ----------
__global__ __launch_bounds__(256) void gcn_hist(
    const int* __restrict__ rows, int* __restrict__ off)
{
    const int e = blockIdx.x * 256 + threadIdx.x;   // NE % 256 == 0
    atomicAdd(&off[rows[e] + 1], 1);
}

// ---------- 2b) scan pass 1 ----------
__global__ __launch_bounds__(1024) void gcn_scan1(
    int* __restrict__ off, int* __restrict__ tsum)
{
    const int tile = blockIdx.x;
    const int i = tile * 1024 + threadIdx.x;
    const int lane = threadIdx.x & 63, wid = threadIdx.x >> 6;
    int acc = (i < SCAN_N) ? off[i] : 0;
#pragma unroll
    for (int s = 1; s < 64; s <<= 1) {
        int t = __shfl_up(acc, s);
        if (lane >= s) acc += t;
    }
    __shared__ int wsum[16];
    if (lane == 63) wsum[wid] = acc;
    __syncthreads();
    if (wid == 0) {
        int wv = (lane < 16) ? wsum[lane] : 0;
#pragma unroll
        for (int s = 1; s < 16; s <<= 1) {
            int t = __shfl_up(wv, s);
            if (lane >= s) wv += t;
        }
        if (lane < 16) wsum[lane] = wv;
    }
    __syncthreads();
    if (wid > 0) acc += wsum[wid - 1];
    if (i < SCAN_N) off[i] = acc;
    if (threadIdx.x == 1023) tsum[tile] = acc;
}

// ---------- 2c) scan pass 2 ----------
__global__ __launch_bounds__(128) void gcn_scan2(int* __restrict__ tsum)
{
    const int tid = threadIdx.x, lane = tid & 63, wid = tid >> 6;
    int acc = (tid < NTILES) ? tsum[tid] : 0;
#pragma unroll
    for (int s = 1; s < 64; s <<= 1) {
        int t = __shfl_up(acc, s);
        if (lane >= s) acc += t;
    }
    __shared__ int w0;
    if (wid == 0 && lane == 63) w0 = acc;
    __syncthreads();
    if (wid == 1) acc += w0;
    if (tid < NTILES) tsum[tid] = acc;
}

// ---------- 2d) scan pass 3 ----------
__global__ __launch_bounds__(1024) void gcn_scan3(
    int* __restrict__ off, const int* __restrict__ tsum)
{
    const int tile = blockIdx.x + 1;
    const int i = tile * 1024 + threadIdx.x;
    if (i < SCAN_N) off[i] += tsum[tile - 1];
}

// ---------- 2e) scatter into CSR order, packed (col,val) ----------
__global__ __launch_bounds__(256) void gcn_csr_scatter(
    const int* __restrict__ rows, const int* __restrict__ cols,
    const float* __restrict__ vals, int* __restrict__ off,
    int2* __restrict__ edges)
{
    const int e = blockIdx.x * 256 + threadIdx.x;   // NE % 256 == 0
    const int r = rows[e];
    const int pos = atomicAdd(&off[r], 1);
    edges[pos] = make_int2(cols[e], __float_as_int(vals[e]));
}

// ---------- 3) gather-aggregate, unroll-by-8 ----------
__global__ __launch_bounds__(256) void gcn_aggregate(
    const int* __restrict__ off, const int2* __restrict__ edges,
    const float* __restrict__ Y, const float* __restrict__ bias,
    float* __restrict__ out)
{
    const int wave = threadIdx.x >> 6, lane = threadIdx.x & 63;
    const int r = blockIdx.x * 4 + wave;            // NN % 4 == 0
    const int start = (r == 0) ? 0 : off[r - 1];
    const int end   = off[r];
    float acc = bias[lane];
    int j = start;
    for (; j + 8 <= end; j += 8) {
        const int2 e0 = edges[j + 0], e1 = edges[j + 1];
        const int2 e2 = edges[j + 2], e3 = edges[j + 3];
        const int2 e4 = edges[j + 4], e5 = edges[j + 5];
        const int2 e6 = edges[j + 6], e7 = edges[j + 7];
        const float y0 = Y[e0.x * D + lane], y1 = Y[e1.x * D + lane];
        const float y2 = Y[e2.x * D + lane], y3 = Y[e3.x * D + lane];
        const float y4 = Y[e4.x * D + lane], y5 = Y[e5.x * D + lane];
        const float y6 = Y[e6.x * D + lane], y7 = Y[e7.x * D + lane];
        acc = fmaf(__int_as_float(e0.y), y0, acc);
        acc = fmaf(__int_as_float(e1.y), y1, acc);
        acc = fmaf(__int_as_float(e2.y), y2, acc);
        acc = fmaf(__int_as_float(e3.y), y3, acc);
        acc = fmaf(__int_as_float(e4.y), y4, acc);
        acc = fmaf(__int_as_float(e5.y), y5, acc);
        acc = fmaf(__int_as_float(e6.y), y6, acc);
        acc = fmaf(__int_as_float(e7.y), y7, acc);
    }
    for (; j < end; ++j) {
        const int2 e = edges[j];
        acc = fmaf(__int_as_float(e.y), Y[e.x * D + lane], acc);
    }
    out[r * D + lane] = acc;
}

// ---------- fallback (round-1 proven path) ----------
__global__ __launch_bounds__(256) void gcn_scatter_kernel(
    const int* __restrict__ rows, const int* __restrict__ cols,
    const float* __restrict__ vals, const float* __restrict__ X,
    float* __restrict__ agg)
{
    const int e    = blockIdx.x * 4 + (threadIdx.x >> 6);
    const int lane = threadIdx.x & 63;
    atomicAdd(&agg[rows[e] * D + lane], vals[e] * X[cols[e] * D + lane]);
}

__global__ __launch_bounds__(256) void gcn_transform_kernel(
    const float* __restrict__ W, const float* __restrict__ bias,
    float* __restrict__ out)
{
    __shared__ float Wl[D][D + 1];
    __shared__ float rowbuf[4][D];
    const int tid = threadIdx.x;
    for (int i = tid; i < D * D; i += 256)
        Wl[i >> 6][i & 63] = W[i];
    const int wave = tid >> 6, lane = tid & 63;
    const int n = blockIdx.x * 4 + wave;
    rowbuf[wave][lane] = out[n * D + lane];
    __syncthreads();
    float acc = bias[lane];
#pragma unroll
    for (int f = 0; f < D; ++f)
        acc += rowbuf[wave][f] * Wl[lane][f];
    out[n * D + lane] = acc;
}

extern "C" void kernel_launch(void* const* d_in, const int* in_sizes, int n_in,
                              void* d_out, int out_size, void* d_ws, size_t ws_size,
                              hipStream_t stream) {
    const int*   L_rows = (const int*)d_in[0];
    const int*   L_cols = (const int*)d_in[1];
    const float* L_vals = (const float*)d_in[2];
    const float* X      = (const float*)d_in[3];
    const float* W      = (const float*)d_in[4];
    const float* b      = (const float*)d_in[5];
    float* out = (float*)d_out;

    if (ws_size >= WS_NEED) {
        char* w = (char*)d_ws;
        float* Y     = (float*)(w + WS_Y);
        int*   off   = (int*)  (w + WS_OFF);
        int*   tsum  = (int*)  (w + WS_TSUM);
        int2*  edges = (int2*) (w + WS_EDG);

        hipMemsetAsync(off, 0, 4 * 100352 + 512, stream);

        gcn_ybuild<<<NN / 16, 256, 0, stream>>>(X, W, Y);
        gcn_hist<<<NE / 256, 256, 0, stream>>>(L_rows, off);
        gcn_scan1<<<NTILES, 1024, 0, stream>>>(off, tsum);
        gcn_scan2<<<1, 128, 0, stream>>>(tsum);
        gcn_scan3<<<NTILES - 1, 1024, 0, stream>>>(off, tsum);
        gcn_csr_scatter<<<NE / 256, 256, 0, stream>>>(L_rows, L_cols, L_vals,
                                                      off, edges);
        gcn_aggregate<<<NN / 4, 256, 0, stream>>>(off, edges, Y, b, out);
    } else {
        hipMemsetAsync(out, 0, (size_t)out_size * sizeof(float), stream);
        gcn_scatter_kernel<<<NE / 4, 256, 0, stream>>>(L_rows, L_cols, L_vals, X, out);
        gcn_transform_kernel<<<NN / 4, 256, 0, stream>>>(W, b, out);
    }
}